// Round 9
// baseline (263.005 us; speedup 1.0000x reference)
//
#include <hip/hip_runtime.h>
#include <hip/hip_fp16.h>
#include <stdint.h>

#define NB 32          // batch size B (fixed by problem)
#define BIN_SHIFT 6    // 64 dst rows per bin
#define BIN_ROWS 64
#define NBINS_MAX 2048 // supports M <= 131072
#define FCHUNK 8192    // edges per fill block (= its contiguous csr region)
#define FTHREADS 1024  // fill threads: 16 waves/block
#define EPT (FCHUNK / FTHREADS)  // edges per thread (8)
#define FGRID_MAX 512  // max fill blocks (nnz <= 4.19M); guarded at launch
#define SRC_BITS 18    // N < 262144 (problem: N = 100000)
#define SRC_MASK ((1u << SRC_BITS) - 1)
#define CAP 2816       // LDS sort capacity (bin mean 2048 + 17 sigma)

// ---------------------------------------------------------------------------
// x (B, N) f32 -> xt (N, B) f16: 32x32 LDS tile transpose.
// fp16 storage halves the gather footprint; accumulation stays fp32.
// ---------------------------------------------------------------------------
__global__ void transpose_x_kernel(const float* __restrict__ x,
                                   __half* __restrict__ xt, int N) {
    __shared__ float tile[32][33];  // +1 pad: avoid bank conflicts
    int n0 = blockIdx.x * 32;
    for (int i = threadIdx.y; i < 32; i += 8) {
        int n = n0 + threadIdx.x;
        tile[i][threadIdx.x] = (n < N) ? x[(size_t)i * N + n] : 0.f;
    }
    __syncthreads();
    for (int i = threadIdx.y; i < 32; i += 8) {
        int n = n0 + i;
        if (n < N) xt[(size_t)n * NB + threadIdx.x] =
            __float2half(tile[threadIdx.x][i]);
    }
}

// ---------------------------------------------------------------------------
// Block-major fill: block k sorts its FCHUNK-edge chunk by bin INSIDE its
// own contiguous csr region [k*FCHUNK, (k+1)*FCHUNK) — writes are 100%
// streaming (every 64B line fully covered), zero write amplification.
// Emits segOff[k][bin] = absolute start of bin's run in block k's region
// (segOff[k][nbins] = region end sentinel). No capacities, no overflow.
// Entry: meta = (dst&63) << SRC_BITS | src, val bits.
// ---------------------------------------------------------------------------
__global__ void fill_bm(const int* __restrict__ src,
                        const int* __restrict__ dst,
                        const float* __restrict__ vals,
                        uint2* __restrict__ csr,
                        int* __restrict__ segOff,
                        int nnz, int nbins) {
    __shared__ int lhist[NBINS_MAX];   // counts, then rank cursors
    __shared__ int lbase[NBINS_MAX];   // exclusive scan of counts
    __shared__ int sscan[FTHREADS];    // block-scan workspace
    int t = threadIdx.x;
    int k = blockIdx.x;
    int e0 = k * FCHUNK;
    int chunk = min(FCHUNK, nnz - e0);
    int dcache[EPT];

    for (int i = t; i < NBINS_MAX; i += FTHREADS) lhist[i] = 0;
    __syncthreads();
#pragma unroll
    for (int q = 0; q < EPT; ++q) {
        int e = e0 + q * FTHREADS + t;
        int d = (e < nnz) ? dst[e] : -1;
        dcache[q] = d;
        if (d >= 0) atomicAdd(&lhist[d >> BIN_SHIFT], 1);
    }
    __syncthreads();
    // block exclusive scan over 2048 bins: 2 per thread + 1024-scan
    int s0 = lhist[2 * t];
    int s1 = lhist[2 * t + 1];
    int tsum = s0 + s1;
    sscan[t] = tsum;
    __syncthreads();
    for (int off = 1; off < FTHREADS; off <<= 1) {
        int add = (t >= off) ? sscan[t - off] : 0;
        __syncthreads();
        sscan[t] += add;
        __syncthreads();
    }
    int excl = sscan[t] - tsum;
    lbase[2 * t]     = excl;
    lbase[2 * t + 1] = excl + s0;
    lhist[2 * t]     = 0;   // reuse as rank cursors
    lhist[2 * t + 1] = 0;
    __syncthreads();
    // segment descriptor row (streaming, contiguous)
    int* row = segOff + (size_t)k * (nbins + 1);
    for (int i = t; i <= nbins; i += FTHREADS)
        row[i] = e0 + ((i < nbins) ? lbase[i] : chunk);
    // ranked write into the block's own region (fully-covered lines)
#pragma unroll
    for (int q = 0; q < EPT; ++q) {
        int e = e0 + q * FTHREADS + t;
        int d = dcache[q];
        if (d >= 0) {
            int bin = d >> BIN_SHIFT;
            int r = lbase[bin] + atomicAdd(&lhist[bin], 1);
            uint32_t meta = ((uint32_t)(d & (BIN_ROWS - 1)) << SRC_BITS) |
                            (uint32_t)src[e];
            csr[e0 + r] = make_uint2(meta, __float_as_uint(vals[e]));
        }
    }
}

// ---------------------------------------------------------------------------
// Fused segment-gather + sort + bias + output-transpose, block per bin:
//  1. read the bin's fgrid segment descriptors (L2-hot), total count;
//  2. counting-sort the bin's edges into LDS (hist pass + scatter pass over
//     the segments; second pass L2-hot);
//  3. each half-wave gathers its rows from the LDS-sorted list: fp16 xt
//     loads, fp32 register accumulation, 8-deep pipeline, no atomics;
//  4. writes DIRECTLY to out (B, M) + bias.
// Bins with cnt > CAP (never for random dst; any-input safety) take an
// LDS-atomic-tile slow path: correct for arbitrary skew.
// ---------------------------------------------------------------------------
__global__ __launch_bounds__(256) void sort_gather(
        const int* __restrict__ segOff,
        const uint2* __restrict__ csr,
        const __half* __restrict__ xt,
        const float* __restrict__ bias,
        float* __restrict__ out, int M, int nbins, int fgrid) {
    __shared__ uint2 sorted[CAP];      // 22 KB (aliased as tile in slow path)
    __shared__ int segBase[FGRID_MAX];
    __shared__ short segCnt[FGRID_MAX];
    __shared__ int rowCnt[BIN_ROWS];
    __shared__ int rowOff[BIN_ROWS];
    __shared__ int totS;
    int t = threadIdx.x;
    int bin = blockIdx.x;
    int g = t >> 5;   // half-wave id 0..7
    int b = t & 31;   // batch lane

    if (t == 0) totS = 0;
    if (t < BIN_ROWS) rowCnt[t] = 0;
    __syncthreads();
    int mySum = 0;
    for (int k = t; k < fgrid; k += 256) {
        const int* row = segOff + (size_t)k * (nbins + 1) + bin;
        int s0 = row[0];
        int s1 = row[1];
        segBase[k] = s0;
        segCnt[k] = (short)(s1 - s0);
        mySum += s1 - s0;
    }
    if (mySum) atomicAdd(&totS, mySum);
    __syncthreads();
    int cnt = totS;

    if (cnt <= CAP) {
        // pass 1: row histogram (meta reads; lines cached for pass 2)
        for (int k = t; k < fgrid; k += 256) {
            int base = segBase[k], n = segCnt[k];
            for (int j = 0; j < n; ++j)
                atomicAdd(&rowCnt[csr[base + j].x >> SRC_BITS], 1);
        }
        __syncthreads();
        if (t == 0) {
            int run = 0;
#pragma unroll
            for (int r = 0; r < BIN_ROWS; ++r) {
                rowOff[r] = run;
                run += rowCnt[r];
            }
        }
        __syncthreads();
        // pass 2: ranked scatter into LDS (csr lines L2-hot from pass 1)
        for (int k = t; k < fgrid; k += 256) {
            int base = segBase[k], n = segCnt[k];
            for (int j = 0; j < n; ++j) {
                uint2 e = csr[base + j];
                int p = atomicAdd(&rowOff[e.x >> SRC_BITS], 1);
                sorted[p] = e;
            }
        }
        __syncthreads();
        // gather: half-wave per row, 8-deep atomic-free pipeline
        for (int r = g; r < BIN_ROWS; r += 8) {
            int m = bin * BIN_ROWS + r;
            if (m >= M) break;
            int jend = rowOff[r];
            int jj   = jend - rowCnt[r];
            float acc0 = 0.f, acc1 = 0.f;
            for (; jj + 8 <= jend; jj += 8) {
                uint2 e0 = sorted[jj + 0];
                uint2 e1 = sorted[jj + 1];
                uint2 e2 = sorted[jj + 2];
                uint2 e3 = sorted[jj + 3];
                uint2 e4 = sorted[jj + 4];
                uint2 e5 = sorted[jj + 5];
                uint2 e6 = sorted[jj + 6];
                uint2 e7 = sorted[jj + 7];
                float x0 = __half2float(xt[(size_t)(e0.x & SRC_MASK) * NB + b]);
                float x1 = __half2float(xt[(size_t)(e1.x & SRC_MASK) * NB + b]);
                float x2 = __half2float(xt[(size_t)(e2.x & SRC_MASK) * NB + b]);
                float x3 = __half2float(xt[(size_t)(e3.x & SRC_MASK) * NB + b]);
                float x4 = __half2float(xt[(size_t)(e4.x & SRC_MASK) * NB + b]);
                float x5 = __half2float(xt[(size_t)(e5.x & SRC_MASK) * NB + b]);
                float x6 = __half2float(xt[(size_t)(e6.x & SRC_MASK) * NB + b]);
                float x7 = __half2float(xt[(size_t)(e7.x & SRC_MASK) * NB + b]);
                acc0 = fmaf(__uint_as_float(e0.y), x0, acc0);
                acc1 = fmaf(__uint_as_float(e1.y), x1, acc1);
                acc0 = fmaf(__uint_as_float(e2.y), x2, acc0);
                acc1 = fmaf(__uint_as_float(e3.y), x3, acc1);
                acc0 = fmaf(__uint_as_float(e4.y), x4, acc0);
                acc1 = fmaf(__uint_as_float(e5.y), x5, acc1);
                acc0 = fmaf(__uint_as_float(e6.y), x6, acc0);
                acc1 = fmaf(__uint_as_float(e7.y), x7, acc1);
            }
            for (; jj < jend; ++jj) {
                uint2 e = sorted[jj];
                acc0 = fmaf(__uint_as_float(e.y),
                            __half2float(xt[(size_t)(e.x & SRC_MASK) * NB + b]),
                            acc0);
            }
            out[(size_t)b * M + m] = acc0 + acc1 + bias[m];
        }
    } else {
        // slow path (arbitrary skew): LDS float-atomic 64x32 tile
        float* tile = (float*)sorted;   // 8 KB of the 22 KB alias
        for (int i = t; i < BIN_ROWS * NB; i += 256) tile[i] = 0.f;
        __syncthreads();
        for (int k = g; k < fgrid; k += 8) {
            int base = segBase[k], n = segCnt[k];
            for (int j = 0; j < n; ++j) {
                uint2 e = csr[base + j];   // broadcast across half-wave
                float xv = __half2float(xt[(size_t)(e.x & SRC_MASK) * NB + b]);
                atomicAdd(&tile[(e.x >> SRC_BITS) * NB + b],
                          __uint_as_float(e.y) * xv);
            }
        }
        __syncthreads();
        for (int i = t; i < BIN_ROWS * NB; i += 256) {
            int m = bin * BIN_ROWS + (i >> 5);
            if (m < M) out[(size_t)(i & 31) * M + m] = tile[i] + bias[m];
        }
    }
}

// ---------------------------------------------------------------------------
// yt (M, B) -> out (B, M), + bias (fallback path only).
// ---------------------------------------------------------------------------
__global__ void finalize_kernel(const float* __restrict__ yt,
                                const float* __restrict__ bias,
                                float* __restrict__ out, int M) {
    __shared__ float tile[32][33];
    int m0 = blockIdx.x * 32;
    for (int i = threadIdx.y; i < 32; i += 8) {
        int m = m0 + i;
        tile[i][threadIdx.x] = (m < M) ? yt[(size_t)m * NB + threadIdx.x] : 0.f;
    }
    __syncthreads();
    for (int i = threadIdx.y; i < 32; i += 8) {
        int m = m0 + threadIdx.x;
        if (m < M) out[(size_t)i * M + m] = tile[threadIdx.x][i] + bias[m];
    }
}

// ---------------------------------------------------------------------------
// Fallback: global-atomic scatter. Used only if ws_size is too small or
// fgrid exceeds the descriptor LDS budget.
// ---------------------------------------------------------------------------
__global__ void scatter_kernel(const int* __restrict__ src,
                               const int* __restrict__ dst,
                               const float* __restrict__ vals,
                               const __half* __restrict__ xt,
                               float* __restrict__ yt, int nnz) {
    long long tid = (long long)blockIdx.x * blockDim.x + threadIdx.x;
    int e = (int)(tid >> 5);
    if (e >= nnz) return;
    int b = (int)(tid & 31);
    atomicAdd(&yt[(size_t)dst[e] * NB + b],
              vals[e] * __half2float(xt[(size_t)src[e] * NB + b]));
}

extern "C" void kernel_launch(void* const* d_in, const int* in_sizes, int n_in,
                              void* d_out, int out_size, void* d_ws, size_t ws_size,
                              hipStream_t stream) {
    const float* x       = (const float*)d_in[0];   // (B, N, 1) fp32
    const int*   indices = (const int*)  d_in[1];   // (2, NNZ) int32
    const float* vals    = (const float*)d_in[2];   // (NNZ,) fp32
    const float* bias    = (const float*)d_in[3];   // (M, 1) fp32

    float* out = (float*)d_out;                     // (B, M, 1) fp32

    int nnz = in_sizes[1] / 2;
    int N   = in_sizes[0] / NB;
    int M   = in_sizes[3];

    const int* src = indices;        // row 0
    const int* dst = indices + nnz;  // row 1

    int nbins = (M + BIN_ROWS - 1) >> BIN_SHIFT;   // 1563 for M=100000
    int fgrid = (nnz + FCHUNK - 1) / FCHUNK;       // 391

    // workspace layout (primary path, ~47 MB):
    //   xt      N*NB f16                (6.4 MB)
    //   yt      M*NB f32                (12.8 MB, fallback only)
    //   segOff  fgrid*(nbins+1) i32     (2.45 MB)
    //   csr     nnz uint2               (25.6 MB)
    __half* xt     = (__half*)d_ws;
    float*  yt     = (float*)(xt + (size_t)N * NB);
    int*    segOff = (int*)(yt + (size_t)M * NB);
    uint2*  csr    = (uint2*)(((uintptr_t)(segOff +
                        (size_t)fgrid * (nbins + 1)) + 15) & ~(uintptr_t)15);

    size_t need = (size_t)((char*)(csr + nnz) - (char*)d_ws);

    transpose_x_kernel<<<(N + 31) / 32, dim3(32, 8), 0, stream>>>(x, xt, N);

    if (ws_size >= need && fgrid <= FGRID_MAX && nbins <= NBINS_MAX) {
        fill_bm<<<fgrid, FTHREADS, 0, stream>>>(src, dst, vals, csr, segOff,
                                                nnz, nbins);
        sort_gather<<<nbins, 256, 0, stream>>>(segOff, csr, xt, bias, out,
                                               M, nbins, fgrid);
    } else {
        // fallback: atomic scatter (needs only xt + yt)
        hipMemsetAsync(yt, 0, (size_t)M * NB * sizeof(float), stream);
        long long pairs = (long long)nnz * NB;
        int grid = (int)((pairs + 255) / 256);
        scatter_kernel<<<grid, 256, 0, stream>>>(src, dst, vals, xt, yt, nnz);
        finalize_kernel<<<(M + 31) / 32, dim3(32, 8), 0, stream>>>(yt, bias,
                                                                   out, M);
    }
}

// Round 10
// 198.105 us; speedup vs baseline: 1.3276x; 1.3276x over previous
//
#include <hip/hip_runtime.h>
#include <hip/hip_fp16.h>
#include <stdint.h>

#define NB 32          // batch size B (fixed by problem)
#define BIN_SHIFT 6    // 64 dst rows per fine bin
#define BIN_ROWS 64
#define NBINS_MAX 2048 // fine bins: supports M <= 131072
#define CSHIFT 10      // 1024 dst rows per coarse bin (16 fine bins)
#define NC_MAX 128     // coarse bins: supports M <= 131072
#define FPC 16         // fine bins per coarse bin
#define FCHUNK 8192    // edges per coarse-fill block
#define FTHREADS 1024
#define EPT (FCHUNK / FTHREADS)      // 8
#define CAP_C 34816    // coarse region capacity: mean 32768 + 11 sigma
#define P2CHUNK 8192   // entries per fine-fill block
#define CH2 ((CAP_C + P2CHUNK - 1) / P2CHUNK)  // 5 chunks per coarse region
#define EPT2 (P2CHUNK / FTHREADS)    // 8
#define SRC_BITS 18    // N < 262144 (problem: N = 100000)
#define SRC_MASK ((1u << SRC_BITS) - 1)
#define CAP 2816       // gather LDS sort capacity (fine-bin mean 2048 + 17 sigma)
#define MAXK 11        // CAP / 256 entries per thread in sort_gather

// meta layout: bits [27:18] = dst & 1023, bits [17:0] = src
//   fine-bin-in-coarse = (meta >> 24) & 15     (= (dst >> 6) & 15)
//   row-in-fine-bin    = (meta >> 18) & 63     (= dst & 63)

// ---------------------------------------------------------------------------
// x (B, N) f32 -> xt (N, B) f16: 32x32 LDS tile transpose.
// ---------------------------------------------------------------------------
__global__ void transpose_x_kernel(const float* __restrict__ x,
                                   __half* __restrict__ xt, int N) {
    __shared__ float tile[32][33];
    int n0 = blockIdx.x * 32;
    for (int i = threadIdx.y; i < 32; i += 8) {
        int n = n0 + threadIdx.x;
        tile[i][threadIdx.x] = (n < N) ? x[(size_t)i * N + n] : 0.f;
    }
    __syncthreads();
    for (int i = threadIdx.y; i < 32; i += 8) {
        int n = n0 + i;
        if (n < N) xt[(size_t)n * NB + threadIdx.x] =
            __float2half(tile[threadIdx.x][i]);
    }
}

// ---------------------------------------------------------------------------
// Pass 1: coarse radix fill. Runs of ~84 edges (670B) per (block,coarse) ->
// near-zero write amplification. Also accumulates the EXACT global fine-bin
// histogram (excluding coarse-overflow edges). Coarse overflow (mean+11sig,
// statistically never) -> edge-id ovList, applied by fixup.
// ---------------------------------------------------------------------------
__global__ void fill_coarse(const int* __restrict__ src,
                            const int* __restrict__ dst,
                            const float* __restrict__ vals,
                            int* __restrict__ cCursor,     // [NC_MAX], rel, 0-init
                            uint2* __restrict__ cCsr,      // [ncoarse*CAP_C]
                            int* __restrict__ fineCnt,     // [nbins], 0-init
                            int* __restrict__ ovCount,
                            int* __restrict__ ovList,
                            int nnz, int ncoarse, int nbins) {
    __shared__ int lhist[NC_MAX];    // coarse counts, then rank cursors
    __shared__ int lbase[NC_MAX];    // claimed relative bases
    __shared__ int fh[NBINS_MAX];    // fine-bin histogram
    int t = threadIdx.x;
    int e0 = blockIdx.x * FCHUNK;
    int dcache[EPT];
    for (int i = t; i < NC_MAX; i += FTHREADS) lhist[i] = 0;
    for (int i = t; i < nbins; i += FTHREADS) fh[i] = 0;
    __syncthreads();
#pragma unroll
    for (int q = 0; q < EPT; ++q) {
        int e = e0 + q * FTHREADS + t;
        int d = (e < nnz) ? dst[e] : -1;
        dcache[q] = d;
        if (d >= 0) atomicAdd(&lhist[d >> CSHIFT], 1);
    }
    __syncthreads();
    for (int i = t; i < ncoarse; i += FTHREADS) {
        int c = lhist[i];
        lbase[i] = c ? atomicAdd(&cCursor[i], c) : 0;
        lhist[i] = 0;  // reuse as rank cursor
    }
    __syncthreads();
#pragma unroll
    for (int q = 0; q < EPT; ++q) {
        int e = e0 + q * FTHREADS + t;
        int d = dcache[q];
        if (d >= 0) {
            int c = d >> CSHIFT;
            int r = lbase[c] + atomicAdd(&lhist[c], 1);
            if (r < CAP_C) {
                uint32_t meta = ((uint32_t)(d & 1023) << SRC_BITS) |
                                (uint32_t)src[e];
                cCsr[(size_t)c * CAP_C + r] =
                    make_uint2(meta, __float_as_uint(vals[e]));
                atomicAdd(&fh[d >> BIN_SHIFT], 1);
            } else {
                int op = atomicAdd(ovCount, 1);
                ovList[op] = e;   // sized nnz: cannot overflow
            }
        }
    }
    __syncthreads();
    for (int i = t; i < nbins; i += FTHREADS)
        if (fh[i]) atomicAdd(&fineCnt[i], fh[i]);
}

// ---------------------------------------------------------------------------
// Exclusive scan of exact fine counts (single block, 1024 thr x 2).
// fineBase = packed start; fineCursor starts == fineBase (pass-2 claims).
// Fine csr is packed EXACTLY: no caps, no fine overflow possible.
// ---------------------------------------------------------------------------
__global__ void fine_scan(const int* __restrict__ fineCnt,
                          int* __restrict__ fineBase,
                          int* __restrict__ fineCursor, int nbins) {
    __shared__ int s[1024];
    int t = threadIdx.x;
    int i0 = t * 2, i1 = t * 2 + 1;
    int v0 = (i0 < nbins) ? fineCnt[i0] : 0;
    int v1 = (i1 < nbins) ? fineCnt[i1] : 0;
    int sum = v0 + v1;
    s[t] = sum;
    __syncthreads();
    for (int off = 1; off < 1024; off <<= 1) {
        int add = (t >= off) ? s[t - off] : 0;
        __syncthreads();
        s[t] += add;
        __syncthreads();
    }
    int run = s[t] - sum;
    if (i0 < nbins) { fineBase[i0] = run; fineCursor[i0] = run; }
    run += v0;
    if (i1 < nbins) { fineBase[i1] = run; fineCursor[i1] = run; }
}

// ---------------------------------------------------------------------------
// Pass 2: fine radix fill. Block (c, i) streams one contiguous 8192-entry
// chunk of coarse region c and ranked-writes into the exactly-packed fine
// csr: 16 runs of ~512 entries (4KB) per block -> streaming writes.
// ---------------------------------------------------------------------------
__global__ void fill_fine(const int* __restrict__ cCursor,
                          const uint2* __restrict__ cCsr,
                          int* __restrict__ fineCursor,
                          uint2* __restrict__ fineCsr) {
    __shared__ int lhist[FPC];
    __shared__ int lbase[FPC];
    int c = blockIdx.x / CH2;
    int i = blockIdx.x % CH2;
    int n  = min(cCursor[c], CAP_C);   // actual entries in region
    int j0 = i * P2CHUNK;
    int jn = min(j0 + P2CHUNK, n);
    if (j0 >= jn) return;              // block-uniform: safe early exit
    int t = threadIdx.x;
    uint2 ecache[EPT2];
    if (t < FPC) lhist[t] = 0;
    __syncthreads();
    const uint2* reg = cCsr + (size_t)c * CAP_C;
#pragma unroll
    for (int q = 0; q < EPT2; ++q) {
        int j = j0 + q * FTHREADS + t;
        if (j < jn) {
            uint2 e = reg[j];
            ecache[q] = e;
            atomicAdd(&lhist[(e.x >> 24) & 15], 1);
        }
    }
    __syncthreads();
    if (t < FPC) {
        int cn = lhist[t];
        lbase[t] = cn ? atomicAdd(&fineCursor[c * FPC + t], cn) : 0;
        lhist[t] = 0;  // reuse as rank cursor
    }
    __syncthreads();
#pragma unroll
    for (int q = 0; q < EPT2; ++q) {
        int j = j0 + q * FTHREADS + t;
        if (j < jn) {
            uint2 e = ecache[q];
            int f = (e.x >> 24) & 15;
            int p = lbase[f] + atomicAdd(&lhist[f], 1);
            fineCsr[p] = e;
        }
    }
}

// ---------------------------------------------------------------------------
// Fused sort + gather + bias + output-transpose, one block per fine bin
// (round-8 proven structure, contiguous [fineBase, fineCursor) input):
//  1. read the bin's entries ONCE into registers; LDS counting-sort by row;
//  2. half-wave per row: fp16 xt gather, fp32 acc, 8-deep pipeline, no
//     atomics; 3. direct write to out (B, M) + bias.
// cnt > CAP (adversarial skew only): LDS-atomic-tile slow path.
// ---------------------------------------------------------------------------
__global__ __launch_bounds__(256) void sort_gather(
        const int* __restrict__ fineBase,
        const int* __restrict__ fineCursor,
        const uint2* __restrict__ csr,
        const __half* __restrict__ xt,
        const float* __restrict__ bias,
        float* __restrict__ out, int M) {
    __shared__ uint2 sorted[CAP];      // 22 KB (aliased as tile in slow path)
    __shared__ int rowCnt[BIN_ROWS];
    __shared__ int rowOff[BIN_ROWS];
    int t = threadIdx.x;
    int bin = blockIdx.x;
    int start = fineBase[bin];
    int cnt   = fineCursor[bin] - start;
    int g = t >> 5;   // half-wave id 0..7
    int b = t & 31;   // batch lane

    if (cnt <= CAP) {
        uint2 reg[MAXK];
#pragma unroll
        for (int k = 0; k < MAXK; ++k) {
            int j = t + k * 256;
            if (j < cnt) reg[k] = csr[start + j];
        }
        if (t < BIN_ROWS) rowCnt[t] = 0;
        __syncthreads();
#pragma unroll
        for (int k = 0; k < MAXK; ++k) {
            int j = t + k * 256;
            if (j < cnt)
                atomicAdd(&rowCnt[(reg[k].x >> SRC_BITS) & 63], 1);
        }
        __syncthreads();
        if (t == 0) {
            int run = 0;
#pragma unroll
            for (int r = 0; r < BIN_ROWS; ++r) {
                rowOff[r] = run;
                run += rowCnt[r];
            }
        }
        __syncthreads();
#pragma unroll
        for (int k = 0; k < MAXK; ++k) {
            int j = t + k * 256;
            if (j < cnt) {
                int p = atomicAdd(&rowOff[(reg[k].x >> SRC_BITS) & 63], 1);
                sorted[p] = reg[k];
            }
        }
        __syncthreads();
        for (int r = g; r < BIN_ROWS; r += 8) {
            int m = bin * BIN_ROWS + r;
            if (m >= M) break;
            int jend = rowOff[r];
            int jj   = jend - rowCnt[r];
            float acc0 = 0.f, acc1 = 0.f;
            for (; jj + 8 <= jend; jj += 8) {
                uint2 e0 = sorted[jj + 0];
                uint2 e1 = sorted[jj + 1];
                uint2 e2 = sorted[jj + 2];
                uint2 e3 = sorted[jj + 3];
                uint2 e4 = sorted[jj + 4];
                uint2 e5 = sorted[jj + 5];
                uint2 e6 = sorted[jj + 6];
                uint2 e7 = sorted[jj + 7];
                float x0 = __half2float(xt[(size_t)(e0.x & SRC_MASK) * NB + b]);
                float x1 = __half2float(xt[(size_t)(e1.x & SRC_MASK) * NB + b]);
                float x2 = __half2float(xt[(size_t)(e2.x & SRC_MASK) * NB + b]);
                float x3 = __half2float(xt[(size_t)(e3.x & SRC_MASK) * NB + b]);
                float x4 = __half2float(xt[(size_t)(e4.x & SRC_MASK) * NB + b]);
                float x5 = __half2float(xt[(size_t)(e5.x & SRC_MASK) * NB + b]);
                float x6 = __half2float(xt[(size_t)(e6.x & SRC_MASK) * NB + b]);
                float x7 = __half2float(xt[(size_t)(e7.x & SRC_MASK) * NB + b]);
                acc0 = fmaf(__uint_as_float(e0.y), x0, acc0);
                acc1 = fmaf(__uint_as_float(e1.y), x1, acc1);
                acc0 = fmaf(__uint_as_float(e2.y), x2, acc0);
                acc1 = fmaf(__uint_as_float(e3.y), x3, acc1);
                acc0 = fmaf(__uint_as_float(e4.y), x4, acc0);
                acc1 = fmaf(__uint_as_float(e5.y), x5, acc1);
                acc0 = fmaf(__uint_as_float(e6.y), x6, acc0);
                acc1 = fmaf(__uint_as_float(e7.y), x7, acc1);
            }
            for (; jj < jend; ++jj) {
                uint2 e = sorted[jj];
                acc0 = fmaf(__uint_as_float(e.y),
                            __half2float(xt[(size_t)(e.x & SRC_MASK) * NB + b]),
                            acc0);
            }
            out[(size_t)b * M + m] = acc0 + acc1 + bias[m];
        }
    } else {
        // slow path (arbitrary skew): LDS float-atomic 64x32 tile over the
        // contiguous fine region
        float* tile = (float*)sorted;   // 8 KB alias
        for (int i = t; i < BIN_ROWS * NB; i += 256) tile[i] = 0.f;
        __syncthreads();
        for (int j = start + g; j < start + cnt; j += 8) {
            uint2 e = csr[j];   // broadcast across half-wave
            float xv = __half2float(xt[(size_t)(e.x & SRC_MASK) * NB + b]);
            atomicAdd(&tile[((e.x >> SRC_BITS) & 63) * NB + b],
                      __uint_as_float(e.y) * xv);
        }
        __syncthreads();
        for (int i = t; i < BIN_ROWS * NB; i += 256) {
            int m = bin * BIN_ROWS + (i >> 5);
            if (m < M) out[(size_t)(i & 31) * M + m] = tile[i] + bias[m];
        }
    }
}

// ---------------------------------------------------------------------------
// Fixup: apply coarse-overflow edges (statistically zero) with global
// atomics into out (B, M). Runs AFTER sort_gather.
// ---------------------------------------------------------------------------
__global__ void fixup_kernel(const int* __restrict__ ovCount,
                             const int* __restrict__ ovList,
                             const int* __restrict__ src,
                             const int* __restrict__ dst,
                             const float* __restrict__ vals,
                             const __half* __restrict__ xt,
                             float* __restrict__ out, int M) {
    long long total = (long long)(*ovCount) * 32;
    long long stride = (long long)gridDim.x * blockDim.x;
    for (long long i = (long long)blockIdx.x * blockDim.x + threadIdx.x;
         i < total; i += stride) {
        int k = (int)(i >> 5);
        int b = (int)(i & 31);
        int e = ovList[k];
        atomicAdd(&out[(size_t)b * M + dst[e]],
                  vals[e] * __half2float(xt[(size_t)src[e] * NB + b]));
    }
}

// ---------------------------------------------------------------------------
// yt (M, B) -> out (B, M), + bias (fallback path only).
// ---------------------------------------------------------------------------
__global__ void finalize_kernel(const float* __restrict__ yt,
                                const float* __restrict__ bias,
                                float* __restrict__ out, int M) {
    __shared__ float tile[32][33];
    int m0 = blockIdx.x * 32;
    for (int i = threadIdx.y; i < 32; i += 8) {
        int m = m0 + i;
        tile[i][threadIdx.x] = (m < M) ? yt[(size_t)m * NB + threadIdx.x] : 0.f;
    }
    __syncthreads();
    for (int i = threadIdx.y; i < 32; i += 8) {
        int m = m0 + threadIdx.x;
        if (m < M) out[(size_t)i * M + m] = tile[threadIdx.x][i] + bias[m];
    }
}

// ---------------------------------------------------------------------------
// Fallback: global-atomic scatter (needs only xt + yt).
// ---------------------------------------------------------------------------
__global__ void scatter_kernel(const int* __restrict__ src,
                               const int* __restrict__ dst,
                               const float* __restrict__ vals,
                               const __half* __restrict__ xt,
                               float* __restrict__ yt, int nnz) {
    long long tid = (long long)blockIdx.x * blockDim.x + threadIdx.x;
    int e = (int)(tid >> 5);
    if (e >= nnz) return;
    int b = (int)(tid & 31);
    atomicAdd(&yt[(size_t)dst[e] * NB + b],
              vals[e] * __half2float(xt[(size_t)src[e] * NB + b]));
}

extern "C" void kernel_launch(void* const* d_in, const int* in_sizes, int n_in,
                              void* d_out, int out_size, void* d_ws, size_t ws_size,
                              hipStream_t stream) {
    const float* x       = (const float*)d_in[0];   // (B, N, 1) fp32
    const int*   indices = (const int*)  d_in[1];   // (2, NNZ) int32
    const float* vals    = (const float*)d_in[2];   // (NNZ,) fp32
    const float* bias    = (const float*)d_in[3];   // (M, 1) fp32

    float* out = (float*)d_out;                     // (B, M, 1) fp32

    int nnz = in_sizes[1] / 2;
    int N   = in_sizes[0] / NB;
    int M   = in_sizes[3];

    const int* src = indices;        // row 0
    const int* dst = indices + nnz;  // row 1

    int nbins   = (M + BIN_ROWS - 1) >> BIN_SHIFT;  // 1563 for M=100000
    int ncoarse = (M + (1 << CSHIFT) - 1) >> CSHIFT; // 98 for M=100000

    // primary workspace layout (~72 MB):
    //   xt         N*NB f16               (6.4 MB)
    //   fineCnt    NBINS_MAX i32          |
    //   cCursor    NC_MAX i32             | one memset-0 region
    //   ovCount    4 i32                  |
    //   fineBase   NBINS_MAX i32          (written by fine_scan)
    //   fineCursor NBINS_MAX i32          (written by fine_scan)
    //   ovList     nnz i32                (12.8 MB)
    //   cCsr       ncoarse*CAP_C uint2    (27.3 MB)
    //   fineCsr    nnz uint2              (25.6 MB)
    __half* xt         = (__half*)d_ws;
    int*    fineCnt    = (int*)(xt + (size_t)N * NB);
    int*    cCursor    = fineCnt + NBINS_MAX;
    int*    ovCount    = cCursor + NC_MAX;
    int*    fineBase   = ovCount + 4;
    int*    fineCursor = fineBase + NBINS_MAX;
    int*    ovList     = fineCursor + NBINS_MAX;
    uint2*  cCsr       = (uint2*)(((uintptr_t)(ovList + nnz) + 15) &
                                  ~(uintptr_t)15);
    uint2*  fineCsr    = cCsr + (size_t)ncoarse * CAP_C;

    size_t need = (size_t)((char*)(fineCsr + nnz) - (char*)d_ws);

    // fallback layout: yt immediately after xt (overlaps primary buffers;
    // the two paths are exclusive)
    float* yt = (float*)(xt + (size_t)N * NB);
    size_t need_fb = (size_t)((char*)(yt + (size_t)M * NB) - (char*)d_ws);

    transpose_x_kernel<<<(N + 31) / 32, dim3(32, 8), 0, stream>>>(x, xt, N);

    if (ws_size >= need && nbins <= NBINS_MAX && ncoarse <= NC_MAX) {
        hipMemsetAsync(fineCnt, 0, (NBINS_MAX + NC_MAX + 4) * sizeof(int),
                       stream);
        int fgrid = (nnz + FCHUNK - 1) / FCHUNK;  // 391
        fill_coarse<<<fgrid, FTHREADS, 0, stream>>>(src, dst, vals, cCursor,
                                                    cCsr, fineCnt, ovCount,
                                                    ovList, nnz, ncoarse,
                                                    nbins);
        fine_scan<<<1, 1024, 0, stream>>>(fineCnt, fineBase, fineCursor,
                                          nbins);
        fill_fine<<<ncoarse * CH2, FTHREADS, 0, stream>>>(cCursor, cCsr,
                                                          fineCursor, fineCsr);
        sort_gather<<<nbins, 256, 0, stream>>>(fineBase, fineCursor, fineCsr,
                                               xt, bias, out, M);
        fixup_kernel<<<32, 256, 0, stream>>>(ovCount, ovList, src, dst, vals,
                                             xt, out, M);
    } else if (ws_size >= need_fb) {
        hipMemsetAsync(yt, 0, (size_t)M * NB * sizeof(float), stream);
        long long pairs = (long long)nnz * NB;
        int grid = (int)((pairs + 255) / 256);
        scatter_kernel<<<grid, 256, 0, stream>>>(src, dst, vals, xt, yt, nnz);
        finalize_kernel<<<(M + 31) / 32, dim3(32, 8), 0, stream>>>(yt, bias,
                                                                   out, M);
    }
}